// Round 9
// baseline (203.398 us; speedup 1.0000x reference)
//
#include <hip/hip_runtime.h>
#include <math.h>

#define BB 128
#define EE 64
#define TT 2048
#define C2 32
#define W1 2049
#define WPW 512
#define FEAT 4096
#define NBLK 1024

// float offsets in ws
#define OFF_P    ((size_t)0)          // bf16 P: 128*32*2048 ushort
#define OFF_X2   ((size_t)4194304)    // bf16 X2
#define OFF_PSUM ((size_t)8388608)    // 32*1024
#define OFF_PSQ  ((size_t)8421376)    // 32*1024
#define OFF_SS   ((size_t)8454144)    // 64
#define OFF_H    ((size_t)8454208)    // fp32 [512][128][33] = 2,162,688
#define OFF_G    ((size_t)10633280)   // fp32 [512][128][33] = 2,162,688

__device__ __forceinline__ unsigned short f2b(float f) {
    unsigned int u = __float_as_uint(f);
    u += 0x7FFFu + ((u >> 16) & 1u);
    return (unsigned short)(u >> 16);
}
__device__ __forceinline__ float b2f(unsigned short s) {
    return __uint_as_float(((unsigned int)s) << 16);
}
__device__ __forceinline__ float elu_fast(float a) {
    return (a > 0.f) ? a : (__expf(a) - 1.f);
}

// ---- P[b,c,t] = sum_e w2[c,e]*in[b,e,t], stored bf16. Direct global reads. ----
__global__ __launch_bounds__(256) void k_p(const float* __restrict__ in,
        const float* __restrict__ w2, unsigned short* __restrict__ P) {
    int b = blockIdx.y, t0 = blockIdx.x * 256, tid = threadIdx.x;
    __shared__ float lw2t[64][32];           // transposed weights, 8 KB
    for (int j = tid; j < 2048; j += 256) {
        int e = j >> 5, c = j & 31;
        lw2t[e][c] = w2[c * 64 + e];
    }
    __syncthreads();
    int cg = tid >> 6, colg = tid & 63;
    int c8 = cg * 8;
    float acc[4][8];
#pragma unroll
    for (int x = 0; x < 4; x++)
#pragma unroll
        for (int jj = 0; jj < 8; jj++) acc[x][jj] = 0.f;
    const float* ibase = in + (size_t)b * EE * TT + t0 + colg * 4;
#pragma unroll 4
    for (int e = 0; e < 64; e++) {
        float4 iv = *(const float4*)(ibase + (size_t)e * TT);   // coalesced; L1 absorbs 4x
        float4 wa = *(const float4*)&lw2t[e][c8];               // broadcast
        float4 wb = *(const float4*)&lw2t[e][c8 + 4];
        float cv[4] = {iv.x, iv.y, iv.z, iv.w};
        float wv[8] = {wa.x, wa.y, wa.z, wa.w, wb.x, wb.y, wb.z, wb.w};
#pragma unroll
        for (int jj = 0; jj < 8; jj++)
#pragma unroll
            for (int x = 0; x < 4; x++)
                acc[x][jj] = fmaf(wv[jj], cv[x], acc[x][jj]);
    }
    unsigned short* Pb = P + (size_t)b * C2 * TT + t0 + colg * 4;
#pragma unroll
    for (int jj = 0; jj < 8; jj++) {
        int c = c8 + jj;
        uint2 o;
        o.x = (unsigned int)f2b(acc[0][jj]) | ((unsigned int)f2b(acc[1][jj]) << 16);
        o.y = (unsigned int)f2b(acc[2][jj]) | ((unsigned int)f2b(acc[3][jj]) << 16);
        *(uint2*)(Pb + (size_t)c * TT) = o;
    }
}

// ---- conv1(32 taps) + sign(bn1_gamma) + X2(bf16) + bn2 partial stats ----
__global__ __launch_bounds__(256) void k_cs(const unsigned short* __restrict__ P,
        const float* __restrict__ w1, const float* __restrict__ g1,
        unsigned short* __restrict__ x2, float* __restrict__ psum, float* __restrict__ psq) {
    int bx = blockIdx.x, b = blockIdx.y, w0 = bx * 256, tid = threadIdx.x;
    __shared__ unsigned short lp[32][288];
    __shared__ float lw1[16][32];
    __shared__ float lds_s[32], lds_q[32];
    const unsigned short* Pb = P + (size_t)b * C2 * TT;
    for (int j = tid; j < 32 * 72; j += 256) {
        int c = j / 72, g4 = j % 72;
        int t = w0 - 16 + g4 * 4;
        uint2 v = make_uint2(0u, 0u);
        if (t >= 0 && t + 3 < TT) v = *(const uint2*)(Pb + (size_t)c * TT + t);
        *(uint2*)&lp[c][g4 * 4] = v;
    }
    for (int j = tid; j < 512; j += 256) {
        int g = j >> 5;
        float sgn = (g1[g] < 0.f) ? -1.f : 1.f;
        lw1[g][j & 31] = w1[j] * sgn;
    }
    __syncthreads();
    for (int r = 0; r < 8; r++) {
        int task = r * 256 + tid;
        int c = task >> 6;          // wave-uniform
        int wq = task & 63;
        int wbase = wq * 4;
        float win[36];
#pragma unroll
        for (int i = 0; i < 9; i++) {
            uint2 v = *(const uint2*)&lp[c][wbase + i * 4];
            win[i * 4 + 0] = __uint_as_float(v.x << 16);
            win[i * 4 + 1] = __uint_as_float(v.x & 0xFFFF0000u);
            win[i * 4 + 2] = __uint_as_float(v.y << 16);
            win[i * 4 + 3] = __uint_as_float(v.y & 0xFFFF0000u);
        }
        const float* wc = lw1[c >> 1];
        float ls = 0.f, lq = 0.f;
        float accs[4];
#pragma unroll
        for (int i = 0; i < 4; i++) {
            float acc = 0.f;
#pragma unroll
            for (int k = 0; k < 32; k++) acc = fmaf(wc[k], win[i + k], acc);
            accs[i] = acc;
            ls += acc; lq = fmaf(acc, acc, lq);
        }
        uint2 o;
        o.x = (unsigned int)f2b(accs[0]) | ((unsigned int)f2b(accs[1]) << 16);
        o.y = (unsigned int)f2b(accs[2]) | ((unsigned int)f2b(accs[3]) << 16);
        *(uint2*)(x2 + ((size_t)b * C2 + c) * TT + w0 + wbase) = o;
#pragma unroll
        for (int d = 1; d < 64; d <<= 1) {
            ls += __shfl_xor(ls, d);
            lq += __shfl_xor(lq, d);
        }
        if ((tid & 63) == 0) { lds_s[c] = ls; lds_q[c] = lq; }
    }
    __syncthreads();
    if (bx == 7 && tid < 32) {      // stats for w=2048
        const float* wc = lw1[tid >> 1];
        float acc = 0.f;
#pragma unroll
        for (int k = 0; k < 16; k++) acc = fmaf(wc[k], b2f(lp[tid][256 + k]), acc);
        lds_s[tid] += acc;
        lds_q[tid] += acc * acc;
    }
    __syncthreads();
    if (tid < 32) {
        int blk = b * 8 + bx;
        psum[tid * NBLK + blk] = lds_s[tid];
        psq[tid * NBLK + blk]  = lds_q[tid];
    }
}

__global__ __launch_bounds__(64) void k_bn2fin(
        const float* __restrict__ psum, const float* __restrict__ psq,
        const float* __restrict__ gamma, const float* __restrict__ beta,
        float* __restrict__ ss) {
    int c = blockIdx.x, l = threadIdx.x;
    float s = 0.f, q = 0.f;
    for (int j = l; j < NBLK; j += 64) { s += psum[c * NBLK + j]; q += psq[c * NBLK + j]; }
#pragma unroll
    for (int d = 1; d < 64; d <<= 1) { s += __shfl_xor(s, d); q += __shfl_xor(q, d); }
    if (l == 0) {
        float n = (float)(BB * W1);
        float m = s / n;
        float var = q / n - m * m;
        float sc = gamma[c] * rsqrtf(var + 1e-3f);
        ss[c] = sc;
        ss[32 + c] = beta[c] - m * sc;
    }
}

// ---- fused: bn2+elu+pool4 + ec1 conv + L2norm + add_time + lc1 matvec + add_time ----
__global__ __launch_bounds__(256) void k_mid(
        const unsigned short* __restrict__ x2, const float* __restrict__ ss,
        const float* __restrict__ ew, const float* __restrict__ lc1,
        float* __restrict__ H) {
    int b = blockIdx.y, w0 = blockIdx.x * 64, tid = threadIdx.x;
    __shared__ __align__(16) float ly[32][82];
    __shared__ float lss[64];
    __shared__ float lew[32][17];
    __shared__ __align__(16) float lxn[8][8][32];
    if (tid < 64) lss[tid] = ss[tid];
    for (int j = tid; j < 512; j += 256) lew[j >> 4][j & 15] = ew[j];
    __syncthreads();
    // pool: 2 outputs per iteration via uint4 (8 bf16)
    const unsigned short* xb = x2 + (size_t)b * C2 * TT;
    for (int it = 0; it < 5; it++) {
        int idx = it * 256 + tid;           // 1280 tasks = 32c * 40 pairs
        int c = idx / 40, m = idx - c * 40;
        int ty = w0 - 8 + 2 * m;
        float r0 = 0.f, r1 = 0.f;
        if (ty >= 0 && ty < WPW) {          // pair fully valid or fully invalid (ty even)
            uint4 v = *(const uint4*)(xb + (size_t)c * TT + ty * 4);
            float sc = lss[c], sh = lss[32 + c];
            r0 = (elu_fast(fmaf(sc, __uint_as_float(v.x << 16), sh))
                + elu_fast(fmaf(sc, __uint_as_float(v.x & 0xFFFF0000u), sh))
                + elu_fast(fmaf(sc, __uint_as_float(v.y << 16), sh))
                + elu_fast(fmaf(sc, __uint_as_float(v.y & 0xFFFF0000u), sh))) * 0.25f;
            r1 = (elu_fast(fmaf(sc, __uint_as_float(v.z << 16), sh))
                + elu_fast(fmaf(sc, __uint_as_float(v.z & 0xFFFF0000u), sh))
                + elu_fast(fmaf(sc, __uint_as_float(v.w << 16), sh))
                + elu_fast(fmaf(sc, __uint_as_float(v.w & 0xFFFF0000u), sh))) * 0.25f;
        }
        ly[c][2 * m] = r0;
        ly[c][2 * m + 1] = r1;
    }
    __syncthreads();
    // ec1: 16-tap depthwise conv, 8 outputs (w's) per thread
    int c = tid & 31, wl = tid >> 5;
    float win[24];
#pragma unroll
    for (int m = 0; m < 12; m++) {
        float2 v = *(const float2*)&ly[c][wl * 8 + m * 2];
        win[m * 2] = v.x; win[m * 2 + 1] = v.y;
    }
    float wc[16];
#pragma unroll
    for (int k = 0; k < 16; k++) wc[k] = lew[c][k];
    float acc[8];
#pragma unroll
    for (int i = 0; i < 8; i++) {
        float a = 0.f;
#pragma unroll
        for (int k = 0; k < 16; k++) a = fmaf(wc[k], win[i + k], a);
        acc[i] = a;
    }
    // head phase A: batched norm reductions + broadcast rows to LDS
    float ss8[8];
#pragma unroll
    for (int i = 0; i < 8; i++) ss8[i] = acc[i] * acc[i];
#pragma unroll
    for (int d = 1; d < 32; d <<= 1) {
#pragma unroll
        for (int i = 0; i < 8; i++) ss8[i] += __shfl_xor(ss8[i], d);
    }
    float pre0[8];
#pragma unroll
    for (int i = 0; i < 8; i++) {
        float inv = 1.f / (sqrtf(ss8[i]) + 1e-8f);
        lxn[wl][i][c] = acc[i] * inv;
        float s2 = ss8[i] * inv * inv;
        pre0[i] = fmaxf(sqrtf(1.f + s2), 1.f);
    }
    // head phase B: per-lane output row o=c+1, weights from L2
    float wt0 = lc1[(c + 1) * 33];
    float wreg[32];
#pragma unroll
    for (int k = 0; k < 32; k++) wreg[k] = lc1[(c + 1) * 33 + 1 + k];
    float y8[8];
#pragma unroll
    for (int i = 0; i < 8; i++) {
        float y = wt0 * pre0[i];
#pragma unroll
        for (int q = 0; q < 8; q++) {
            float4 xv = *(const float4*)&lxn[wl][i][q * 4];
            y = fmaf(wreg[q * 4 + 0], xv.x, y);
            y = fmaf(wreg[q * 4 + 1], xv.y, y);
            y = fmaf(wreg[q * 4 + 2], xv.z, y);
            y = fmaf(wreg[q * 4 + 3], xv.w, y);
        }
        y8[i] = y;
    }
    float sy8[8];
#pragma unroll
    for (int i = 0; i < 8; i++) sy8[i] = y8[i] * y8[i];
#pragma unroll
    for (int d = 1; d < 32; d <<= 1) {
#pragma unroll
        for (int i = 0; i < 8; i++) sy8[i] += __shfl_xor(sy8[i], d);
    }
#pragma unroll
    for (int i = 0; i < 8; i++) {
        int w = w0 + wl * 8 + i;
        float* hrow = H + ((size_t)w * BB + b) * 33;
        hrow[1 + c] = y8[i];
        if (c == 0) hrow[0] = sqrtf(1.f + sy8[i]);
    }
}

// ---- lorentz_bn + elu: one w per block, 2 lanes per (w,b) row -> G[w][b][33] ----
__global__ __launch_bounds__(256) void k_tail2(
        const float* __restrict__ H, const float* __restrict__ bs,
        float* __restrict__ G) {
    int w = blockIdx.x;
    int tid = threadIdx.x;
    int l = tid & 1, b = tid >> 1;
    int wv = tid >> 6;
    __shared__ float wsum[4][2][17];
    __shared__ float vsum[4];
    float x[17];
    const float* hp = H + ((size_t)w * BB + b) * 33;
#pragma unroll
    for (int k = 0; k < 17; k++) {
        int ch = 2 * k + l;
        x[k] = (ch < 33) ? hp[ch] : 0.f;
    }
    float mu[17];
#pragma unroll
    for (int k = 0; k < 17; k++) mu[k] = x[k];
#pragma unroll
    for (int d = 2; d < 64; d <<= 1) {
#pragma unroll
        for (int k = 0; k < 17; k++) mu[k] += __shfl_xor(mu[k], d);
    }
    if ((tid & 63) < 2) {
#pragma unroll
        for (int k = 0; k < 17; k++) wsum[wv][tid & 1][k] = mu[k];
    }
    __syncthreads();
#pragma unroll
    for (int k = 0; k < 17; k++)
        mu[k] = (wsum[0][l][k] + wsum[1][l][k] + wsum[2][l][k] + wsum[3][l][k]) * (1.f / 128.f);
    float a0 = (l == 0) ? mu[0] : 0.f;
    a0 += __shfl_xor(a0, 1);
    float spp = 0.f;
#pragma unroll
    for (int k = 0; k < 17; k++) spp = fmaf(mu[k], mu[k], spp);
    if (l == 0) spp -= 2.f * mu[0] * mu[0];
    spp += __shfl_xor(spp, 1);
    float rd = rsqrtf(fmaxf(-spp, 1e-8f));
#pragma unroll
    for (int k = 0; k < 17; k++) mu[k] *= rd;
    float mu0 = a0 * rd;
    float pp = 0.f;
#pragma unroll
    for (int k = 0; k < 17; k++) pp = fmaf(x[k], mu[k], pp);
    if (l == 0) pp -= 2.f * x[0] * mu[0];
    pp += __shfl_xor(pp, 1);
    float xin = -pp;
    float dist = acoshf(fmaxf(xin, 1.f + 1e-7f));
    float dq = dist * dist;
#pragma unroll
    for (int d = 2; d < 64; d <<= 1) dq += __shfl_xor(dq, d);
    if ((tid & 63) == 0) vsum[wv] = dq;
    __syncthreads();
    float var = (vsum[0] + vsum[1] + vsum[2] + vsum[3]) * (1.f / 128.f);
#pragma unroll
    for (int k = 0; k < 17; k++) x[k] = x[k] - xin * mu[k];
    float lup = 0.f;
#pragma unroll
    for (int k = 0; k < 17; k++) lup = fmaf(x[k], x[k], lup);
    if (l == 0) lup -= 2.f * x[0] * x[0];
    lup += __shfl_xor(lup, 1);
    float f = dist * rsqrtf(fmaxf(lup, 1e-8f));
#pragma unroll
    for (int k = 0; k < 17; k++) x[k] *= f;
    float v0 = (l == 0) ? x[0] : 0.f;
    v0 += __shfl_xor(v0, 1);
    float corr = -v0 / (1.f + mu0);
#pragma unroll
    for (int k = 0; k < 17; k++) x[k] = fmaf(corr, mu[k], x[k]);
    if (l == 0) x[0] += corr;
    float scb = bs[w] * rsqrtf(var + 1e-5f);
#pragma unroll
    for (int k = 0; k < 17; k++) x[k] *= scb;
    float nnp = 0.f;
#pragma unroll
    for (int k = 0; k < 17; k++) nnp = fmaf(x[k], x[k], nnp);
    if (l == 0) nnp -= 2.f * x[0] * x[0];
    nnp += __shfl_xor(nnp, 1);
    float n = sqrtf(fmaxf(nnp, 1e-9f));
    float shn = sinhf(n) / n;
    float e[17];
#pragma unroll
    for (int k = 0; k < 17; k++) e[k] = elu_fast(shn * x[k]);
    float sgp = 0.f;
#pragma unroll
    for (int k = 0; k < 17; k++) sgp = fmaf(e[k], e[k], sgp);
    if (l == 0) sgp -= e[0] * e[0];
    sgp += __shfl_xor(sgp, 1);
    float g0 = sqrtf(1.f + sgp);
    float* gp = G + ((size_t)w * BB + b) * 33;
#pragma unroll
    for (int k = 0; k < 17; k++) {
        int ch = 2 * k + l;
        if (ch >= 1 && ch < 33) gp[ch] = e[k];
    }
    if (l == 0) gp[0] = g0;
}

// ---- merged: lorentz pool + flatten + tnew + mlr logits. One block per b. ----
__global__ __launch_bounds__(256) void k_pm(
        const float* __restrict__ G, const float* __restrict__ z,
        const float* __restrict__ a, float* __restrict__ outp) {
    int b = blockIdx.x, tid = threadIdx.x;
    __shared__ float feats[128 * 33];       // padded rows: [wp][33]
    __shared__ float qs[128];
    __shared__ float red[4][8];
    __shared__ float tnsh;
    if (tid < 128) {
        int wp = tid;
        float avg[33];
#pragma unroll
        for (int ch = 0; ch < 33; ch++) avg[ch] = 0.f;
        for (int j = 0; j < 4; j++) {
            const float* gp = G + ((size_t)(wp * 4 + j) * BB + b) * 33;
#pragma unroll
            for (int ch = 0; ch < 33; ch++) avg[ch] += gp[ch];
        }
#pragma unroll
        for (int ch = 0; ch < 33; ch++) avg[ch] *= 0.25f;
        float sp2 = 0.f;
#pragma unroll
        for (int i = 1; i < 33; i++) sp2 = fmaf(avg[i], avg[i], sp2);
        float lnr = avg[0] * avg[0] - sp2;
        float rd2 = rsqrtf(fmaxf(lnr, 1e-8f));
        float q0 = avg[0] * rd2;
        qs[wp] = q0 * q0;
#pragma unroll
        for (int i = 1; i < 33; i++) feats[wp * 33 + (i - 1)] = avg[i] * rd2;
    }
    __syncthreads();
    if (tid < 64) {
        float s = qs[tid] + qs[tid + 64];
#pragma unroll
        for (int d = 1; d < 64; d <<= 1) s += __shfl_xor(s, d);
        if (tid == 0) tnsh = sqrtf(fmaxf(s - 127.f, 1e-8f));
    }
    __syncthreads();
    float tn = tnsh;
    float* fb = outp + 512 + (size_t)b * 4097;
    for (int i = tid; i < 4096; i += 256) fb[1 + i] = feats[i + (i >> 5)];
    if (tid == 0) fb[0] = tn;
    float sdot[4] = {0.f, 0.f, 0.f, 0.f}, sq[4] = {0.f, 0.f, 0.f, 0.f};
    for (int k = 0; k < 16; k++) {
        int j = tid + k * 256;
        float fv = feats[j + (j >> 5)];
#pragma unroll
        for (int c = 0; c < 4; c++) {
            float zv = z[c * FEAT + j];
            sdot[c] = fmaf(fv, zv, sdot[c]);
            sq[c]   = fmaf(zv, zv, sq[c]);
        }
    }
#pragma unroll
    for (int d = 1; d < 64; d <<= 1) {
#pragma unroll
        for (int c = 0; c < 4; c++) {
            sdot[c] += __shfl_xor(sdot[c], d);
            sq[c]   += __shfl_xor(sq[c], d);
        }
    }
    int wv = tid >> 6;
    if ((tid & 63) == 0) {
#pragma unroll
        for (int c = 0; c < 4; c++) { red[wv][c] = sdot[c]; red[wv][4 + c] = sq[c]; }
    }
    __syncthreads();
    if (tid == 0) {
#pragma unroll
        for (int c = 0; c < 4; c++) {
            float dot = red[0][c] + red[1][c] + red[2][c] + red[3][c];
            float qz  = red[0][4 + c] + red[1][4 + c] + red[2][4 + c] + red[3][4 + c];
            float nz = sqrtf(qz);
            float ca = coshf(a[c]), sa = sinhf(a[c]);
            float wt = sa * nz;
            float cb = ca * nz;
            float bb = sqrtf(fmaxf(cb * cb - wt * wt, 1e-8f));
            float alpha = fmaf(-tn, wt, ca * dot);
            float d = fabsf(asinhf(alpha / bb));
            float sg = (alpha > 0.f) ? 1.f : ((alpha < 0.f) ? -1.f : 0.f);
            outp[b * 4 + c] = sg * bb * d;
        }
    }
}

extern "C" void kernel_launch(void* const* d_in, const int* in_sizes, int n_in,
                              void* d_out, int out_size, void* d_ws, size_t ws_size,
                              hipStream_t stream) {
    const float* in   = (const float*)d_in[0];
    const float* w1   = (const float*)d_in[2];
    const float* g1   = (const float*)d_in[3];
    const float* w2   = (const float*)d_in[5];
    const float* g2   = (const float*)d_in[6];
    const float* b2   = (const float*)d_in[7];
    const float* ew   = (const float*)d_in[8];
    const float* lc1  = (const float*)d_in[9];
    const float* bs   = (const float*)d_in[10];
    const float* mlra = (const float*)d_in[11];
    const float* mlrz = (const float*)d_in[12];
    float* out = (float*)d_out;
    float* ws = (float*)d_ws;

    unsigned short* P  = (unsigned short*)(ws + OFF_P);
    unsigned short* X2 = (unsigned short*)(ws + OFF_X2);
    float* PSUM = ws + OFF_PSUM;
    float* PSQ  = ws + OFF_PSQ;
    float* SS   = ws + OFF_SS;
    float* H    = ws + OFF_H;
    float* G    = ws + OFF_G;

    k_p<<<dim3(8, 128), 256, 0, stream>>>(in, w2, P);
    k_cs<<<dim3(8, 128), 256, 0, stream>>>(P, w1, g1, X2, PSUM, PSQ);
    k_bn2fin<<<32, 64, 0, stream>>>(PSUM, PSQ, g2, b2, SS);
    k_mid<<<dim3(8, 128), 256, 0, stream>>>(X2, SS, ew, lc1, H);
    k_tail2<<<512, 256, 0, stream>>>(H, bs, G);
    k_pm<<<128, 256, 0, stream>>>(G, mlrz, mlra, out);
}